// Round 5
// baseline (511.121 us; speedup 1.0000x reference)
//
#include <hip/hip_runtime.h>
#include <cstdint>

#define B_SZ 8192
#define D_SZ 1024
#define E_SZ 16
#define H_SZ 1024
#define MAXTILES 544   // >= sum_e ceil(count_e/128) worst case (512+16)

using short8 = __attribute__((ext_vector_type(8))) short;
using f32x4  = __attribute__((ext_vector_type(4))) float;

__device__ __forceinline__ unsigned short f2bf(float f) {
  union { float f; unsigned int u; } v; v.f = f;
  unsigned int u = v.u;
  return (unsigned short)((u + 0x7fffu + ((u >> 16) & 1u)) >> 16);  // RNE
}
__device__ __forceinline__ float bf2f(unsigned short h) {
  union { unsigned int u; float f; } v; v.u = ((unsigned int)h) << 16; return v.f;
}

__device__ __forceinline__ void async_ld16(void* lds, const void* g) {
  __builtin_amdgcn_global_load_lds(
      reinterpret_cast<const unsigned int __attribute__((address_space(1)))*>(
          reinterpret_cast<uintptr_t>(g)),
      reinterpret_cast<unsigned int __attribute__((address_space(3)))*>(
          reinterpret_cast<uintptr_t>(lds)),
      16, 0, 0);
}

// ============ prep: fused gating_logits + xcast + wtconv ============
__global__ __launch_bounds__(256) void prep(
    const float* __restrict__ x, const float* __restrict__ wg,
    const float* __restrict__ wn, const float* __restrict__ ew,
    unsigned short* __restrict__ xb, unsigned short* __restrict__ wtb,
    float* __restrict__ cl, float* __restrict__ rn, float* __restrict__ stats) {
  __shared__ __align__(16) char psm[16640];
  const int bx = blockIdx.x;
  const int tid = threadIdx.x;

  if (bx < 512) {
    // ---- gating_logits: 16 rows/block, thread (rg,c) does 2 rows x 1 col ----
    float (*sx)[128] = (float(*)[128])psm;
    const int c  = tid & 31;
    const int rg = tid >> 5;
    const int rowbase = bx * 16;
    const float* wp = (c < 16) ? (wg + c) : (wn + (c - 16));
    float acc0 = 0.f, acc1 = 0.f;
    for (int ch = 0; ch < 8; ++ch) {
      __syncthreads();
      #pragma unroll
      for (int it = 0; it < 2; ++it) {
        const int idx = it * 256 + tid;
        const int r = idx >> 5, co = (idx & 31) * 4;
        *(float4*)&sx[r][co] =
            *(const float4*)(x + (size_t)(rowbase + r) * D_SZ + ch * 128 + co);
      }
      __syncthreads();
      #pragma unroll 4
      for (int d = 0; d < 128; ++d) {
        const float wv = wp[(size_t)(ch * 128 + d) * 16];
        acc0 = fmaf(sx[rg * 2][d],     wv, acc0);
        acc1 = fmaf(sx[rg * 2 + 1][d], wv, acc1);
      }
    }
    const int row0 = rowbase + rg * 2;
    if (c < 16) {
      cl[(size_t)row0 * 16 + c] = acc0;
      cl[(size_t)(row0 + 1) * 16 + c] = acc1;
    } else {
      rn[(size_t)row0 * 16 + (c - 16)] = acc0;
      rn[(size_t)(row0 + 1) * 16 + (c - 16)] = acc1;
    }
  } else if (bx < 4608) {
    // ---- xcast: fp32 -> bf16, 8 floats/thread ----
    const int b = bx - 512;
    const size_t i = (size_t)b * 256 + tid;   // short8 index
    const float4 v0 = ((const float4*)x)[2 * i];
    const float4 v1 = ((const float4*)x)[2 * i + 1];
    unsigned short r[8] = {f2bf(v0.x), f2bf(v0.y), f2bf(v0.z), f2bf(v0.w),
                           f2bf(v1.x), f2bf(v1.y), f2bf(v1.z), f2bf(v1.w)};
    ((short8*)xb)[i] = *(const short8*)r;
    if (b == 0 && tid < 48) stats[tid] = 0.0f;
  } else {
    // ---- wtconv: expert_w (E,D,H) fp32 -> Wt (E,H,D) bf16, vectorized ----
    float (*t)[65] = (float(*)[65])psm;
    const int b = bx - 4608;
    const int e  = b >> 8;
    const int d0 = ((b >> 4) & 15) * 64;
    const int h0 = (b & 15) * 64;
    const float* We = ew + (size_t)e * D_SZ * H_SZ;
    unsigned short* Wte = wtb + (size_t)e * D_SZ * H_SZ;
    #pragma unroll
    for (int i = 0; i < 4; ++i) {
      const int idx = i * 256 + tid;
      const int r = idx >> 4, co = (idx & 15) * 4;
      *(float4*)&t[r][co] =
          *(const float4*)(We + (size_t)(d0 + r) * H_SZ + h0 + co);
    }
    __syncthreads();
    #pragma unroll
    for (int i = 0; i < 2; ++i) {
      const int idx = i * 256 + tid;
      const int r = idx >> 3, c8 = (idx & 7) * 8;
      unsigned short v[8];
      #pragma unroll
      for (int j = 0; j < 8; ++j) v[j] = f2bf(t[c8 + j][r]);
      *(short8*)(Wte + (size_t)(h0 + r) * D_SZ + d0 + c8) = *(const short8*)v;
    }
  }
}

// ---------------- per-row gating: softmax, top-9, gates, load/importance, lists ----
__global__ __launch_bounds__(64) void gating_post(
    const float* __restrict__ clg, const float* __restrict__ rng,
    const float* __restrict__ noise, float* __restrict__ gates,
    float* __restrict__ stats, int* __restrict__ rowidx, int* __restrict__ rowmap) {
  int* gcount = (int*)(stats + 32);
  __shared__ int lcnt[16];
  __shared__ int lbase[16];
  const int row = blockIdx.x * 64 + threadIdx.x;
  if (threadIdx.x < 16) lcnt[threadIdx.x] = 0;
  float cl[16], sd[16], nl[16], p[16];
  #pragma unroll
  for (int e = 0; e < 16; ++e) {
    cl[e] = clg[(size_t)row * 16 + e];
    const float r = rng[(size_t)row * 16 + e];
    sd[e] = fmaxf(r, 0.0f) + log1pf(expf(-fabsf(r))) + 0.01f;  // softplus + eps
    nl[e] = cl[e] + noise[(size_t)row * 16 + e] * sd[e];
  }
  float mx = nl[0];
  #pragma unroll
  for (int e = 1; e < 16; ++e) mx = fmaxf(mx, nl[e]);
  float sum = 0.0f;
  #pragma unroll
  for (int e = 0; e < 16; ++e) { p[e] = expf(nl[e] - mx); sum += p[e]; }
  const float inv = 1.0f / sum;
  #pragma unroll
  for (int e = 0; e < 16; ++e) p[e] *= inv;
  float tmp[16];
  #pragma unroll
  for (int e = 0; e < 16; ++e) tmp[e] = p[e];
  float tv[9]; int ti[9];
  for (int k = 0; k < 9; ++k) {
    float bv = tmp[0]; int bj = 0;
    #pragma unroll
    for (int j = 1; j < 16; ++j) if (tmp[j] > bv) { bv = tmp[j]; bj = j; }
    tv[k] = bv; ti[k] = bj; tmp[bj] = -1.0f;
  }
  float s8 = 0.0f;
  #pragma unroll
  for (int k = 0; k < 8; ++k) s8 += tv[k];
  const float denom = s8 + 1e-6f;
  float g[16];
  #pragma unroll
  for (int e = 0; e < 16; ++e) g[e] = 0.0f;
  for (int k = 0; k < 8; ++k) g[ti[k]] = tv[k] / denom;
  const float thr_in = tv[8], thr_out = tv[7];
  float lc[16];
  #pragma unroll
  for (int e = 0; e < 16; ++e) {
    const float t = (nl[e] > thr_in) ? thr_in : thr_out;
    lc[e] = 0.5f * (1.0f + erff(((cl[e] - t) / sd[e]) * 0.70710678118654752f));
  }
  #pragma unroll
  for (int e = 0; e < 16; ++e) gates[(size_t)row * 16 + e] = g[e];
  __syncthreads();
  int myslot[8];
  #pragma unroll
  for (int k = 0; k < 8; ++k) myslot[k] = atomicAdd(&lcnt[ti[k]], 1);
  __syncthreads();
  if (threadIdx.x < 16) lbase[threadIdx.x] = atomicAdd(&gcount[threadIdx.x], lcnt[threadIdx.x]);
  __syncthreads();
  #pragma unroll
  for (int k = 0; k < 8; ++k) {
    const int e = ti[k];
    const int slot = lbase[e] + myslot[k];
    rowidx[e * B_SZ + slot] = row;
    rowmap[row * 8 + k] = (e << 13) | slot;
  }
  #pragma unroll
  for (int e = 0; e < 16; ++e) {
    float vi = g[e], vl = lc[e];
    for (int o = 32; o > 0; o >>= 1) { vi += __shfl_down(vi, o); vl += __shfl_down(vl, o); }
    if (threadIdx.x == 0) {
      atomicAdd(&stats[e], vi);
      atomicAdd(&stats[16 + e], vl);
    }
  }
}

// ---- sparse gather GEMM, one 256-col slab: partial[slot][cs..] = g*(Xb@We^T+eb) ----
// partial slab (~35 MB) stays LLC-resident: written here, read by the immediately
// following reduce_slab, overwritten by the next slab. Regular (cached) stores.
__global__ __launch_bounds__(256, 4) void moe_gemm(
    const unsigned short* __restrict__ Xb,   // [B][D] bf16
    const unsigned short* __restrict__ Wt,   // [E][H][D] bf16
    const float* __restrict__ gates,         // [B][E]
    const float* __restrict__ ebias,         // [E][H]
    const float* __restrict__ stats,         // counts at +32
    const int* __restrict__ rowidx,          // [E][B]
    unsigned short* __restrict__ partial,    // [padded slots][256] bf16
    int col_slab) {
  __shared__ __align__(16) char smem[34816 + 512 + 512];
  unsigned short* sA = (unsigned short*)smem;
  unsigned short* sB = (unsigned short*)(smem + 16384);
  unsigned short* sOut = (unsigned short*)smem;          // 128 x 136 ushorts
  float* sGG = (float*)(smem + 34816);
  int*   sRI = (int*)(smem + 34816 + 512);

  // ---- self-scan: find (expert, tile) for this block ----
  const int* gcount = (const int*)(stats + 32);
  int my_e = -1, tile = 0, tstart = 0, acc_t = 0;
  #pragma unroll
  for (int ee = 0; ee < 16; ++ee) {
    const int nt_e = (gcount[ee] + 127) >> 7;
    if (my_e < 0 && (int)blockIdx.y < acc_t + nt_e) {
      my_e = ee; tile = blockIdx.y - acc_t; tstart = acc_t;
    }
    acc_t += nt_e;
  }
  if (my_e < 0) return;
  const int e = my_e;
  const int slot0 = tile << 7;
  const int cnt = gcount[e];
  const int cs   = blockIdx.x << 7;          // col within slab: 0 or 128
  const int col0 = col_slab * 256 + cs;      // global col
  const int pb = tstart << 7;

  const int tid  = threadIdx.x;
  const int lane = tid & 63;
  const int wave = tid >> 6;
  const int wm = wave >> 1, wn = wave & 1;
  const int ml = lane & 15;
  const int quad = lane >> 4;
  const int wbase = tid & ~63;

  if (tid < 128) {
    const int slot = slot0 + tid;
    const int ok = slot < cnt;
    const int row = ok ? rowidx[e * B_SZ + slot] : 0;
    sRI[tid] = row;
    sGG[tid] = ok ? gates[(size_t)row * 16 + e] : 0.0f;
  }
  float ebv[4];
  #pragma unroll
  for (int j = 0; j < 4; ++j)
    ebv[j] = ebias[(size_t)e * H_SZ + col0 + wn * 64 + j * 16 + ml];
  __syncthreads();

  const unsigned short* We = Wt + (size_t)e * D_SZ * H_SZ;
  const unsigned short* aptr[4];
  const unsigned short* bptr[4];
  #pragma unroll
  for (int i = 0; i < 4; ++i) {
    const int s = i * 256 + tid;
    const int m = s >> 3, pp = s & 7;
    const int gc = pp ^ (m & 7);
    aptr[i] = Xb + (size_t)sRI[m] * D_SZ + gc * 8;
    bptr[i] = We + (size_t)(col0 + m) * D_SZ + gc * 8;
  }

  f32x4 acc[4][4] = {};
  for (int kb = 0; kb < 16; ++kb) {
    const int k0 = kb * 64;
    __syncthreads();
    #pragma unroll
    for (int i = 0; i < 4; ++i)
      async_ld16(sA + (size_t)(i * 256 + wbase) * 8, aptr[i] + k0);
    #pragma unroll
    for (int i = 0; i < 4; ++i)
      async_ld16(sB + (size_t)(i * 256 + wbase) * 8, bptr[i] + k0);
    __syncthreads();
    #pragma unroll
    for (int kk = 0; kk < 2; ++kk) {
      short8 af[4], bfr[4];
      #pragma unroll
      for (int i = 0; i < 4; ++i) {
        const int m = wm * 64 + i * 16 + ml;
        const int cA = kk * 4 + quad;
        af[i]  = *(const short8*)(sA + ((size_t)m * 8 + (cA ^ (m & 7))) * 8);
        const int n = wn * 64 + i * 16 + ml;
        bfr[i] = *(const short8*)(sB + ((size_t)n * 8 + (cA ^ (n & 7))) * 8);
      }
      #pragma unroll
      for (int i = 0; i < 4; ++i)
        #pragma unroll
        for (int j = 0; j < 4; ++j)
          acc[i][j] = __builtin_amdgcn_mfma_f32_16x16x32_bf16(af[i], bfr[j], acc[i][j], 0, 0, 0);
    }
  }

  // ---- epilogue: gate*(acc+bias) -> LDS tile -> full-line cached stores ----
  __syncthreads();
  #pragma unroll
  for (int i = 0; i < 4; ++i) {
    const int mbase = wm * 64 + i * 16 + quad * 4;
    #pragma unroll
    for (int r = 0; r < 4; ++r) {
      const int mrow = mbase + r;
      const float gv = sGG[mrow];
      #pragma unroll
      for (int j = 0; j < 4; ++j) {
        const int cc = wn * 64 + j * 16 + ml;
        sOut[mrow * 136 + cc] = f2bf(gv * (acc[i][j][r] + ebv[j]));
      }
    }
  }
  __syncthreads();
  const size_t prow0 = (size_t)(pb + slot0);
  #pragma unroll
  for (int it = 0; it < 8; ++it) {
    const int s = it * 256 + tid;
    const int rr = s >> 4;
    const int c8 = (s & 15) * 8;
    const short8 v = *(const short8*)(sOut + rr * 136 + c8);
    *(short8*)(partial + (prow0 + rr) * 256 + cs + c8) = v;
  }
}

// ---------------- per-row reduce of 8 partials for one 256-col slab ----------
// 8 rows/block, thread (r=tid>>5, c=(tid&31)*8)
__global__ __launch_bounds__(256) void reduce_slab(
    const unsigned short* __restrict__ partial, const int* __restrict__ rowmap,
    const float* __restrict__ stats, float* __restrict__ y, int col_slab) {
  const int row0 = blockIdx.x * 8;
  const int tid = threadIdx.x;
  const int* gcount = (const int*)(stats + 32);
  __shared__ int sp[8][8];
  if (tid < 64) {
    const int r = tid >> 3, k = tid & 7;
    const int v = rowmap[(row0 + r) * 8 + k];
    const int e = v >> 13, slot = v & 8191;
    int t = 0;
    #pragma unroll
    for (int ee = 0; ee < 16; ++ee) t += (ee < e) ? ((gcount[ee] + 127) >> 7) : 0;
    sp[r][k] = (t << 7) + slot;
  }
  __syncthreads();
  const int r = tid >> 5;
  const int c = (tid & 31) * 8;
  float a[8] = {0.f, 0.f, 0.f, 0.f, 0.f, 0.f, 0.f, 0.f};
  #pragma unroll
  for (int k = 0; k < 8; ++k) {
    const short8 pv = *(const short8*)(partial + (size_t)sp[r][k] * 256 + c);
    #pragma unroll
    for (int j = 0; j < 8; ++j) a[j] += bf2f((unsigned short)pv[j]);
  }
  float4 o0 = {a[0], a[1], a[2], a[3]};
  float4 o1 = {a[4], a[5], a[6], a[7]};
  float* yp = y + (size_t)(row0 + r) * H_SZ + col_slab * 256 + c;
  *(float4*)yp = o0;
  *(float4*)(yp + 4) = o1;

  // ---- loss finalize (once, on the first slab) ----
  if (col_slab == 0 && blockIdx.x == 0 && tid == 0) {
    double si = 0.0, sl = 0.0;
    for (int e = 0; e < 16; ++e) { si += stats[e]; sl += stats[16 + e]; }
    const double mi = si / 16.0, mld = sl / 16.0;
    double vi = 0.0, vl = 0.0;
    for (int e = 0; e < 16; ++e) {
      const double di = stats[e] - mi;       vi += di * di;
      const double dl = stats[16 + e] - mld; vl += dl * dl;
    }
    vi /= 15.0; vl /= 15.0;  // ddof=1
    const double loss = 0.01 * (vi / (mi * mi + 1e-10) + vl / (mld * mld + 1e-10));
    y[(size_t)B_SZ * H_SZ] = (float)loss;
  }
}

extern "C" void kernel_launch(void* const* d_in, const int* in_sizes, int n_in,
                              void* d_out, int out_size, void* d_ws, size_t ws_size,
                              hipStream_t stream) {
  (void)in_sizes; (void)n_in; (void)out_size; (void)ws_size;
  const float* x    = (const float*)d_in[0];
  const float* wg   = (const float*)d_in[1];
  const float* wnoi = (const float*)d_in[2];
  const float* ew   = (const float*)d_in[3];
  const float* eb   = (const float*)d_in[4];
  const float* nz   = (const float*)d_in[5];
  float* y = (float*)d_out;

  char* ws = (char*)d_ws;
  const size_t MB = 1024 * 1024;
  unsigned short* xb     = (unsigned short*)(ws);                 // 16 MB
  unsigned short* wtb    = (unsigned short*)(ws + 16 * MB);       // 32 MB
  float* cl              = (float*)(ws + 48 * MB);                // 512 KB
  float* rn              = (float*)(ws + 48 * MB + 512 * 1024);   // 512 KB
  float* gates           = (float*)(ws + 49 * MB);                // 512 KB
  int*   rowidx          = (int*)  (ws + 49 * MB + 512 * 1024);   // 512 KB
  int*   rowmap          = (int*)  (ws + 50 * MB);                // 256 KB
  float* stats           = (float*)(ws + 50 * MB + 512 * 1024);   // 32 f32 + 16 counts
  unsigned short* partial= (unsigned short*)(ws + 52 * MB);       // ~35 MB slab

  hipLaunchKernelGGL(prep,        dim3(8704),      dim3(256), 0, stream,
                     x, wg, wnoi, ew, xb, wtb, cl, rn, stats);
  hipLaunchKernelGGL(gating_post, dim3(128),       dim3(64),  0, stream,
                     cl, rn, nz, gates, stats, rowidx, rowmap);
  for (int s = 0; s < 4; ++s) {
    hipLaunchKernelGGL(moe_gemm,    dim3(2, MAXTILES), dim3(256), 0, stream,
                       xb, wtb, gates, eb, stats, rowidx, partial, s);
    hipLaunchKernelGGL(reduce_slab, dim3(1024),        dim3(256), 0, stream,
                       partial, rowmap, stats, y, s);
  }
}

// Round 6
// 406.952 us; speedup vs baseline: 1.2560x; 1.2560x over previous
//
#include <hip/hip_runtime.h>
#include <cstdint>

#define B_SZ 8192
#define D_SZ 1024
#define E_SZ 16
#define H_SZ 1024
#define MAXTILES 544   // >= sum_e ceil(count_e/128) worst case (512+16)

using short8 = __attribute__((ext_vector_type(8))) short;
using f32x4  = __attribute__((ext_vector_type(4))) float;

__device__ __forceinline__ unsigned short f2bf(float f) {
  union { float f; unsigned int u; } v; v.f = f;
  unsigned int u = v.u;
  return (unsigned short)((u + 0x7fffu + ((u >> 16) & 1u)) >> 16);  // RNE
}
__device__ __forceinline__ float bf2f(unsigned short h) {
  union { unsigned int u; float f; } v; v.u = ((unsigned int)h) << 16; return v.f;
}

__device__ __forceinline__ void async_ld16(void* lds, const void* g) {
  __builtin_amdgcn_global_load_lds(
      reinterpret_cast<const unsigned int __attribute__((address_space(1)))*>(
          reinterpret_cast<uintptr_t>(g)),
      reinterpret_cast<unsigned int __attribute__((address_space(3)))*>(
          reinterpret_cast<uintptr_t>(lds)),
      16, 0, 0);
}

// ============ prep: fused gating_logits + xcast + wtconv ============
// blocks [0,256): gating_logits (32 rows, LDS-staged x AND w -> no global-latency
//                 stalls in the FMA loop; split: wave=8 cols, lane=(row, d-half))
// blocks [256,4352): xcast;  [4352,8448): wtconv
__global__ __launch_bounds__(256) void prep(
    const float* __restrict__ x, const float* __restrict__ wg,
    const float* __restrict__ wn, const float* __restrict__ ew,
    unsigned short* __restrict__ xb, unsigned short* __restrict__ wtb,
    float* __restrict__ cl, float* __restrict__ rn, float* __restrict__ stats) {
  __shared__ __align__(16) float psm[2 * 32 * 132];   // sx[32][132] + swT[32][132]
  const int bx = blockIdx.x;
  const int tid = threadIdx.x;

  if (bx < 256) {
    float* sx  = psm;              // [row][d] stride 132
    float* swT = psm + 32 * 132;   // [c][d]   stride 132 (c<16: wg, c>=16: wn)
    const int lane = tid & 63;
    const int wave = tid >> 6;
    const int row  = lane & 31;
    const int half = lane >> 5;          // d-half within chunk
    const int rowbase = bx * 32;
    float acc[8] = {0.f, 0.f, 0.f, 0.f, 0.f, 0.f, 0.f, 0.f};

    const int srow = tid >> 3;           // x staging: 32 floats/row/thread-group
    const int sd   = (tid & 7) * 16;
    const int wd   = tid >> 1;           // w staging: d row, 16 cols
    const int wc   = (tid & 1) * 16;
    const float* wsrc = (wc == 0) ? wg : wn;

    for (int ch = 0; ch < 8; ++ch) {
      __syncthreads();
      // stage x chunk: 32 rows x 128 d
      #pragma unroll
      for (int k = 0; k < 4; ++k) {
        const float4 v = *(const float4*)(
            x + (size_t)(rowbase + srow) * D_SZ + ch * 128 + sd + k * 4);
        *(float4*)&sx[srow * 132 + sd + k * 4] = v;
      }
      // stage w chunk transposed: swT[c][d] for c in [wc, wc+16)
      {
        const float* wp = wsrc + (size_t)(ch * 128 + wd) * 16;
        float wv[16];
        #pragma unroll
        for (int k = 0; k < 4; ++k)
          *(float4*)&wv[k * 4] = *(const float4*)(wp + k * 4);
        #pragma unroll
        for (int j = 0; j < 16; ++j) swT[(wc + j) * 132 + wd] = wv[j];
      }
      __syncthreads();
      // compute: each lane: its row, its d-half (64 d), 8 cols (wave*8..+7)
      #pragma unroll 4
      for (int dg = 0; dg < 16; ++dg) {
        const int d = half * 64 + dg * 4;
        const f32x4 xv = *(const f32x4*)&sx[row * 132 + d];
        #pragma unroll
        for (int c = 0; c < 8; ++c) {
          const f32x4 wv = *(const f32x4*)&swT[(wave * 8 + c) * 132 + d];
          acc[c] = fmaf(xv[0], wv[0], acc[c]);
          acc[c] = fmaf(xv[1], wv[1], acc[c]);
          acc[c] = fmaf(xv[2], wv[2], acc[c]);
          acc[c] = fmaf(xv[3], wv[3], acc[c]);
        }
      }
    }
    // combine the two d-halves (lane r += lane r+32)
    #pragma unroll
    for (int c = 0; c < 8; ++c) acc[c] += __shfl_down(acc[c], 32);
    if (lane < 32) {
      const int cg = wave * 8;       // global col 0..31
      float* dst = (cg < 16) ? (cl + (size_t)(rowbase + row) * 16 + cg)
                             : (rn + (size_t)(rowbase + row) * 16 + (cg - 16));
      *(float4*)dst = *(const float4*)&acc[0];
      *(float4*)(dst + 4) = *(const float4*)&acc[4];
    }
  } else if (bx < 4352) {
    // ---- xcast: fp32 -> bf16, 8 floats/thread ----
    const int b = bx - 256;
    const size_t i = (size_t)b * 256 + tid;   // short8 index
    const float4 v0 = ((const float4*)x)[2 * i];
    const float4 v1 = ((const float4*)x)[2 * i + 1];
    unsigned short r[8] = {f2bf(v0.x), f2bf(v0.y), f2bf(v0.z), f2bf(v0.w),
                           f2bf(v1.x), f2bf(v1.y), f2bf(v1.z), f2bf(v1.w)};
    ((short8*)xb)[i] = *(const short8*)r;
    if (b == 0 && tid < 48) stats[tid] = 0.0f;
  } else {
    // ---- wtconv: expert_w (E,D,H) fp32 -> Wt (E,H,D) bf16, vectorized ----
    float (*t)[65] = (float(*)[65])psm;
    const int b = bx - 4352;
    const int e  = b >> 8;
    const int d0 = ((b >> 4) & 15) * 64;
    const int h0 = (b & 15) * 64;
    const float* We = ew + (size_t)e * D_SZ * H_SZ;
    unsigned short* Wte = wtb + (size_t)e * D_SZ * H_SZ;
    #pragma unroll
    for (int i = 0; i < 4; ++i) {
      const int idx = i * 256 + tid;
      const int r = idx >> 4, co = (idx & 15) * 4;
      *(float4*)&t[r][co] =
          *(const float4*)(We + (size_t)(d0 + r) * H_SZ + h0 + co);
    }
    __syncthreads();
    #pragma unroll
    for (int i = 0; i < 2; ++i) {
      const int idx = i * 256 + tid;
      const int r = idx >> 3, c8 = (idx & 7) * 8;
      unsigned short v[8];
      #pragma unroll
      for (int j = 0; j < 8; ++j) v[j] = f2bf(t[c8 + j][r]);
      *(short8*)(Wte + (size_t)(h0 + r) * D_SZ + d0 + c8) = *(const short8*)v;
    }
  }
}

// ---------------- per-row gating: softmax, top-9, gates, load/importance, lists ----
__global__ __launch_bounds__(64) void gating_post(
    const float* __restrict__ clg, const float* __restrict__ rng,
    const float* __restrict__ noise, float* __restrict__ gates,
    float* __restrict__ stats, int* __restrict__ rowidx, int* __restrict__ rowmap) {
  int* gcount = (int*)(stats + 32);
  __shared__ int lcnt[16];
  __shared__ int lbase[16];
  const int row = blockIdx.x * 64 + threadIdx.x;
  if (threadIdx.x < 16) lcnt[threadIdx.x] = 0;
  float cl[16], sd[16], nl[16], p[16];
  #pragma unroll
  for (int e = 0; e < 16; ++e) {
    cl[e] = clg[(size_t)row * 16 + e];
    const float r = rng[(size_t)row * 16 + e];
    sd[e] = fmaxf(r, 0.0f) + log1pf(expf(-fabsf(r))) + 0.01f;  // softplus + eps
    nl[e] = cl[e] + noise[(size_t)row * 16 + e] * sd[e];
  }
  float mx = nl[0];
  #pragma unroll
  for (int e = 1; e < 16; ++e) mx = fmaxf(mx, nl[e]);
  float sum = 0.0f;
  #pragma unroll
  for (int e = 0; e < 16; ++e) { p[e] = expf(nl[e] - mx); sum += p[e]; }
  const float inv = 1.0f / sum;
  #pragma unroll
  for (int e = 0; e < 16; ++e) p[e] *= inv;
  float tmp[16];
  #pragma unroll
  for (int e = 0; e < 16; ++e) tmp[e] = p[e];
  float tv[9]; int ti[9];
  for (int k = 0; k < 9; ++k) {
    float bv = tmp[0]; int bj = 0;
    #pragma unroll
    for (int j = 1; j < 16; ++j) if (tmp[j] > bv) { bv = tmp[j]; bj = j; }
    tv[k] = bv; ti[k] = bj; tmp[bj] = -1.0f;
  }
  float s8 = 0.0f;
  #pragma unroll
  for (int k = 0; k < 8; ++k) s8 += tv[k];
  const float denom = s8 + 1e-6f;
  float g[16];
  #pragma unroll
  for (int e = 0; e < 16; ++e) g[e] = 0.0f;
  for (int k = 0; k < 8; ++k) g[ti[k]] = tv[k] / denom;
  const float thr_in = tv[8], thr_out = tv[7];
  float lc[16];
  #pragma unroll
  for (int e = 0; e < 16; ++e) {
    const float t = (nl[e] > thr_in) ? thr_in : thr_out;
    lc[e] = 0.5f * (1.0f + erff(((cl[e] - t) / sd[e]) * 0.70710678118654752f));
  }
  #pragma unroll
  for (int e = 0; e < 16; ++e) gates[(size_t)row * 16 + e] = g[e];
  __syncthreads();
  int myslot[8];
  #pragma unroll
  for (int k = 0; k < 8; ++k) myslot[k] = atomicAdd(&lcnt[ti[k]], 1);
  __syncthreads();
  if (threadIdx.x < 16) lbase[threadIdx.x] = atomicAdd(&gcount[threadIdx.x], lcnt[threadIdx.x]);
  __syncthreads();
  #pragma unroll
  for (int k = 0; k < 8; ++k) {
    const int e = ti[k];
    const int slot = lbase[e] + myslot[k];
    rowidx[e * B_SZ + slot] = row;
    rowmap[row * 8 + k] = (e << 13) | slot;
  }
  #pragma unroll
  for (int e = 0; e < 16; ++e) {
    float vi = g[e], vl = lc[e];
    for (int o = 32; o > 0; o >>= 1) { vi += __shfl_down(vi, o); vl += __shfl_down(vl, o); }
    if (threadIdx.x == 0) {
      atomicAdd(&stats[e], vi);
      atomicAdd(&stats[16 + e], vl);
    }
  }
}

// ---------------- sparse gather GEMM: partial[pslot] = g * (Xb[rows] @ We^T + eb) --
// grid = (8 cols, MAXTILES): col fastest -> col pins to XCD, A-tile cols co-dispatch.
__global__ __launch_bounds__(256, 4) void moe_gemm(
    const unsigned short* __restrict__ Xb,   // [B][D] bf16
    const unsigned short* __restrict__ Wt,   // [E][H][D] bf16
    const float* __restrict__ gates,         // [B][E]
    const float* __restrict__ ebias,         // [E][H]
    const float* __restrict__ stats,         // counts at +32
    const int* __restrict__ rowidx,          // [E][B]
    unsigned short* __restrict__ partial) {  // [padded slots][H] bf16
  __shared__ __align__(16) char smem[34816 + 512 + 512];
  unsigned short* sA = (unsigned short*)smem;
  unsigned short* sB = (unsigned short*)(smem + 16384);
  unsigned short* sOut = (unsigned short*)smem;          // 128 x 136 ushorts
  float* sGG = (float*)(smem + 34816);
  int*   sRI = (int*)(smem + 34816 + 512);

  // ---- self-scan: find (expert, tile) for this block ----
  const int* gcount = (const int*)(stats + 32);
  int my_e = -1, tile = 0, tstart = 0, acc_t = 0;
  #pragma unroll
  for (int ee = 0; ee < 16; ++ee) {
    const int nt_e = (gcount[ee] + 127) >> 7;
    if (my_e < 0 && (int)blockIdx.y < acc_t + nt_e) {
      my_e = ee; tile = blockIdx.y - acc_t; tstart = acc_t;
    }
    acc_t += nt_e;
  }
  if (my_e < 0) return;
  const int e = my_e;
  const int slot0 = tile << 7;
  const int cnt = gcount[e];
  const int col0 = blockIdx.x << 7;
  const int pb = tstart << 7;

  const int tid  = threadIdx.x;
  const int lane = tid & 63;
  const int wave = tid >> 6;
  const int wm = wave >> 1, wn = wave & 1;
  const int ml = lane & 15;
  const int quad = lane >> 4;
  const int wbase = tid & ~63;

  if (tid < 128) {
    const int slot = slot0 + tid;
    const int ok = slot < cnt;
    const int row = ok ? rowidx[e * B_SZ + slot] : 0;
    sRI[tid] = row;
    sGG[tid] = ok ? gates[(size_t)row * 16 + e] : 0.0f;
  }
  float ebv[4];
  #pragma unroll
  for (int j = 0; j < 4; ++j)
    ebv[j] = ebias[(size_t)e * H_SZ + col0 + wn * 64 + j * 16 + ml];
  __syncthreads();

  const unsigned short* We = Wt + (size_t)e * D_SZ * H_SZ;
  const unsigned short* aptr[4];
  const unsigned short* bptr[4];
  #pragma unroll
  for (int i = 0; i < 4; ++i) {
    const int s = i * 256 + tid;
    const int m = s >> 3, pp = s & 7;
    const int gc = pp ^ (m & 7);
    aptr[i] = Xb + (size_t)sRI[m] * D_SZ + gc * 8;
    bptr[i] = We + (size_t)(col0 + m) * D_SZ + gc * 8;
  }

  f32x4 acc[4][4] = {};
  for (int kb = 0; kb < 16; ++kb) {
    const int k0 = kb * 64;
    __syncthreads();
    #pragma unroll
    for (int i = 0; i < 4; ++i)
      async_ld16(sA + (size_t)(i * 256 + wbase) * 8, aptr[i] + k0);
    #pragma unroll
    for (int i = 0; i < 4; ++i)
      async_ld16(sB + (size_t)(i * 256 + wbase) * 8, bptr[i] + k0);
    __syncthreads();
    #pragma unroll
    for (int kk = 0; kk < 2; ++kk) {
      short8 af[4], bfr[4];
      #pragma unroll
      for (int i = 0; i < 4; ++i) {
        const int m = wm * 64 + i * 16 + ml;
        const int cA = kk * 4 + quad;
        af[i]  = *(const short8*)(sA + ((size_t)m * 8 + (cA ^ (m & 7))) * 8);
        const int n = wn * 64 + i * 16 + ml;
        bfr[i] = *(const short8*)(sB + ((size_t)n * 8 + (cA ^ (n & 7))) * 8);
      }
      #pragma unroll
      for (int i = 0; i < 4; ++i)
        #pragma unroll
        for (int j = 0; j < 4; ++j)
          acc[i][j] = __builtin_amdgcn_mfma_f32_16x16x32_bf16(af[i], bfr[j], acc[i][j], 0, 0, 0);
    }
  }

  // ---- epilogue: gate*(acc+bias) -> LDS tile -> full-line nt stores ----
  __syncthreads();
  #pragma unroll
  for (int i = 0; i < 4; ++i) {
    const int mbase = wm * 64 + i * 16 + quad * 4;
    #pragma unroll
    for (int r = 0; r < 4; ++r) {
      const int mrow = mbase + r;
      const float gv = sGG[mrow];
      #pragma unroll
      for (int j = 0; j < 4; ++j) {
        const int cc = wn * 64 + j * 16 + ml;
        sOut[mrow * 136 + cc] = f2bf(gv * (acc[i][j][r] + ebv[j]));
      }
    }
  }
  __syncthreads();
  const size_t prow0 = (size_t)(pb + slot0);
  #pragma unroll
  for (int it = 0; it < 8; ++it) {
    const int s = it * 256 + tid;
    const int rr = s >> 4;
    const int c8 = (s & 15) * 8;
    const short8 v = *(const short8*)(sOut + rr * 136 + c8);
    __builtin_nontemporal_store(
        v, (short8*)(partial + (prow0 + rr) * H_SZ + col0 + c8));
  }
}

// ---------------- per-row reduce of 8 partials (+ loss finalize) ----------
// 4 rows/block, 2048 blocks; thread = (row r=tid>>6, 16-short seg (tid&63)*16)
__global__ __launch_bounds__(256) void reduce_k(
    const unsigned short* __restrict__ partial, const int* __restrict__ rowmap,
    const float* __restrict__ stats, float* __restrict__ y) {
  const int row0 = blockIdx.x * 4;
  const int tid = threadIdx.x;
  const int* gcount = (const int*)(stats + 32);
  __shared__ int sp[4][8];
  if (tid < 32) {
    const int r = tid >> 3, k = tid & 7;
    const int v = rowmap[(row0 + r) * 8 + k];
    const int e = v >> 13, slot = v & 8191;
    int t = 0;
    #pragma unroll
    for (int ee = 0; ee < 16; ++ee) t += (ee < e) ? ((gcount[ee] + 127) >> 7) : 0;
    sp[r][k] = (t << 7) + slot;
  }
  __syncthreads();
  const int r = tid >> 6;
  const int c0 = (tid & 63) * 16;
  float a[16];
  #pragma unroll
  for (int j = 0; j < 16; ++j) a[j] = 0.f;
  #pragma unroll
  for (int k = 0; k < 8; ++k) {
    const unsigned short* pp = partial + (size_t)sp[r][k] * H_SZ + c0;
    const short8 p0 = *(const short8*)pp;
    const short8 p1 = *(const short8*)(pp + 8);
    #pragma unroll
    for (int j = 0; j < 8; ++j) {
      a[j]     += bf2f((unsigned short)p0[j]);
      a[j + 8] += bf2f((unsigned short)p1[j]);
    }
  }
  float* yp = y + (size_t)(row0 + r) * H_SZ + c0;
  #pragma unroll
  for (int q = 0; q < 4; ++q) {
    float4 o = {a[q * 4], a[q * 4 + 1], a[q * 4 + 2], a[q * 4 + 3]};
    *(float4*)(yp + q * 4) = o;
  }

  // ---- loss finalize (one thread of one block) ----
  if (blockIdx.x == 0 && tid == 0) {
    double si = 0.0, sl = 0.0;
    for (int e = 0; e < 16; ++e) { si += stats[e]; sl += stats[16 + e]; }
    const double mi = si / 16.0, mld = sl / 16.0;
    double vi = 0.0, vl = 0.0;
    for (int e = 0; e < 16; ++e) {
      const double di = stats[e] - mi;       vi += di * di;
      const double dl = stats[16 + e] - mld; vl += dl * dl;
    }
    vi /= 15.0; vl /= 15.0;  // ddof=1
    const double loss = 0.01 * (vi / (mi * mi + 1e-10) + vl / (mld * mld + 1e-10));
    y[(size_t)B_SZ * H_SZ] = (float)loss;
  }
}

extern "C" void kernel_launch(void* const* d_in, const int* in_sizes, int n_in,
                              void* d_out, int out_size, void* d_ws, size_t ws_size,
                              hipStream_t stream) {
  (void)in_sizes; (void)n_in; (void)out_size; (void)ws_size;
  const float* x    = (const float*)d_in[0];
  const float* wg   = (const float*)d_in[1];
  const float* wnoi = (const float*)d_in[2];
  const float* ew   = (const float*)d_in[3];
  const float* eb   = (const float*)d_in[4];
  const float* nz   = (const float*)d_in[5];
  float* y = (float*)d_out;

  char* ws = (char*)d_ws;
  const size_t MB = 1024 * 1024;
  unsigned short* xb     = (unsigned short*)(ws);                 // 16 MB
  unsigned short* wtb    = (unsigned short*)(ws + 16 * MB);       // 32 MB
  float* cl              = (float*)(ws + 48 * MB);                // 512 KB
  float* rn              = (float*)(ws + 48 * MB + 512 * 1024);   // 512 KB
  float* gates           = (float*)(ws + 49 * MB);                // 512 KB
  int*   rowidx          = (int*)  (ws + 49 * MB + 512 * 1024);   // 512 KB
  int*   rowmap          = (int*)  (ws + 50 * MB);                // 256 KB
  float* stats           = (float*)(ws + 50 * MB + 512 * 1024);   // 32 f32 + 16 counts
  unsigned short* partial= (unsigned short*)(ws + 52 * MB);       // ~138 MB

  hipLaunchKernelGGL(prep,        dim3(8448),        dim3(256), 0, stream,
                     x, wg, wnoi, ew, xb, wtb, cl, rn, stats);
  hipLaunchKernelGGL(gating_post, dim3(128),         dim3(64),  0, stream,
                     cl, rn, nz, gates, stats, rowidx, rowmap);
  hipLaunchKernelGGL(moe_gemm,    dim3(8, MAXTILES), dim3(256), 0, stream,
                     xb, wtb, gates, eb, stats, rowidx, partial);
  hipLaunchKernelGGL(reduce_k,    dim3(2048),        dim3(256), 0, stream,
                     partial, rowmap, stats, y);
}